// Round 7
// baseline (216.763 us; speedup 1.0000x reference)
//
#include <hip/hip_runtime.h>
#include <math.h>

#define B_DIM 4
#define L_DIM 8192
#define H_DIM 256
#define P_DIM 256
#define M_DIM (B_DIM * L_DIM)   // 32768 rows (b,l) flattened
#define NC 64                   // scan chunks per chain (chunk = 128 rows = one k1 tile)
#define LC 128                  // chunk length

typedef __attribute__((ext_vector_type(8))) short bf16x8;
typedef __attribute__((ext_vector_type(4))) float f32x4;

static __device__ __forceinline__ float bf2f(unsigned int u) {
    union { unsigned int i; float f; } v; v.i = u << 16; return v.f;
}
static __device__ __forceinline__ unsigned short f2bf(float f) {
    union { float f; unsigned int i; } v; v.f = f;
    unsigned int r = v.i + 0x7FFFu + ((v.i >> 16) & 1u);
    return (unsigned short)(r >> 16);
}
// tanh-form GELU; |gelu_tanh - gelu_erf| <= ~0.003 absolute, far under threshold
static __device__ __forceinline__ float gelu_f(float x) {
    float z = 0.7978845608028654f * (x + 0.044715f * x * x * x);
    float e = __expf(2.0f * z);
    float t = 1.0f - 2.0f / (e + 1.0f);   // tanh(z)
    return 0.5f * x * (1.0f + t);
}
// async global->LDS DMA, 16B per lane; LDS dest = base + lane*16 (wave-uniform base)
static __device__ __forceinline__ void async_load16(const void* g, void* l) {
    __builtin_amdgcn_global_load_lds(
        (const __attribute__((address_space(1))) unsigned int*)g,
        (__attribute__((address_space(3))) unsigned int*)l, 16, 0, 0);
}

// ---------------- combined prep + xcast kernel ----------------
// gid < 2097152: xcast (float4 -> bf16x4).  Then Bmat / B3 / Lbar ranges.
// Layouts (INTERLEAVED complex): Bu col index k = d*512 + 2p + comp.
// Bmat[k][h] (1024x256 bf16); B3[d][h][k'] (2x256x512 bf16), k'=2p+comp;
// LbarWS[d*256+p] = (Lbar_r, Lbar_i) fp32.
__global__ void prep_kernel(const float* fLr, const float* fIm, const float* fLd,
                            const float* fBr, const float* fBi,
                            const float* fCr, const float* fCi,
                            const float* bLr, const float* bIm, const float* bLd,
                            const float* bBr, const float* bBi,
                            const float* bCr, const float* bCi,
                            const float4* __restrict__ x4, ushort4* __restrict__ xb,
                            unsigned short* Bmat, unsigned short* B3, float2* LbarWS) {
    int gid = blockIdx.x * 256 + threadIdx.x;
    if (gid < 2097152) {
        float4 v = x4[gid];
        ushort4 o;
        o.x = f2bf(v.x); o.y = f2bf(v.y); o.z = f2bf(v.z); o.w = f2bf(v.w);
        xb[gid] = o;
        return;
    }
    int g1 = gid - 2097152;
    if (g1 < 262144) {
        // Bmat
        int k = g1 >> 8, h = g1 & 255;
        int d = k >> 9, pc = k & 511, p = pc >> 1, comp = pc & 1;
        const float* LR = d ? bLr : fLr;
        const float* IM = d ? bIm : fIm;
        const float* LD = d ? bLd : fLd;
        const float* BR = d ? bBr : fBr;
        const float* BI = d ? bBi : fBi;
        float Lr = -expf(LR[p]);
        float Li = IM[p];
        float Delta = expf(LD[p]);
        float ea = expf(Lr * Delta);
        float bd = Li * Delta;
        float Lbr = ea * cosf(bd);
        float Lbi = ea * sinf(bd);
        float denom = fmaxf(Lr * Lr + Li * Li, 1e-12f);
        float ivr = Lr / denom, ivi = -Li / denom;
        float dr = Lbr - 1.0f, di = Lbi;
        float cr = ivr * dr - ivi * di;
        float ci = ivr * di + ivi * dr;
        float br = BR[p * 256 + h], bi = BI[p * 256 + h];
        float val = comp ? (cr * bi + ci * br) : (cr * br - ci * bi);
        Bmat[g1] = f2bf(val);
    } else if (g1 < 524288) {
        int g2 = g1 - 262144;
        int d = g2 >> 17;
        int rem = g2 & 131071;
        int h = rem >> 9;
        int kk = rem & 511;
        int p = kk >> 1, comp = kk & 1;
        const float* CR = d ? bCr : fCr;
        const float* CI = d ? bCi : fCi;
        float val = comp ? -CI[h * 256 + p] : CR[h * 256 + p];
        B3[g2] = f2bf(val);
    } else if (g1 < 524800) {
        int g2 = g1 - 524288;          // 0..511
        int d = g2 >> 8, p = g2 & 255;
        const float* LR = d ? bLr : fLr;
        const float* IM = d ? bIm : fIm;
        const float* LD = d ? bLd : fLd;
        float Lr = -expf(LR[p]); float Li = IM[p]; float Delta = expf(LD[p]);
        float ea = expf(Lr * Delta); float bd = Li * Delta;
        LbarWS[g2] = make_float2(ea * cosf(bd), ea * sinf(bd));
    }
}

// ---------------- K1: Bu = xbf(32768x256) @ Bmat(1024x256)^T -> Bu bf16 (32768x1024) ----------------
// m97 geometry: 256 threads / 4 waves, 128x128 tile, wave = 64x64 quadrant (4x4 f32x4 accs),
// BK=64, XOR-swizzled LDS chunks (16B chunk q of row r at q^(r&7); 0 conflicts verified).
// Grid is (Nb=8, Mb=256): the 8 blocks sharing an A-tile are dispatch-adjacent -> L2/L3 reuse.
// Epilogue: C tile -> LDS -> coalesced Bu store + fused per-chunk scan carries
// (full-chunk carry AND inner half-chunk partial, enabling 64-step scan_fix blocks).
__global__ __launch_bounds__(256, 2) void k1_gemm(const unsigned short* __restrict__ A,
                                                  const unsigned short* __restrict__ Bm,
                                                  unsigned short* __restrict__ Bu,
                                                  const float2* __restrict__ Lbar,
                                                  float2* __restrict__ carry,
                                                  float2* __restrict__ halfc) {
    __shared__ unsigned short SH[16384];   // 32 KB: As=SH[0:8192], Bs=SH[8192:16384]; Cs overlays all
    __shared__ float2 Sbuf[64];
    int tid = threadIdx.x;
    int lane = tid & 63, wv = tid >> 6;          // 4 waves
    int wm = (wv >> 1) * 64, wn = (wv & 1) * 64; // 64x64 quadrant
    int Mb = blockIdx.y * 128, Nb = blockIdx.x * 128;
    int lr = lane >> 3;                 // row within 8-row chunk group
    int swz = ((lane & 7) ^ lr) * 8;    // swizzled source chunk (in shorts)
    f32x4 acc[4][4];
#pragma unroll
    for (int i = 0; i < 4; i++)
#pragma unroll
        for (int j = 0; j < 4; j++) acc[i][j] = (f32x4){0.f, 0.f, 0.f, 0.f};
    int mrow = lane & 15, quad = lane >> 4;
    for (int kb = 0; kb < 256; kb += 64) {
#pragma unroll
        for (int ch = wv; ch < 16; ch += 4) {
            int r = ch * 8 + lr;
            async_load16(A  + (size_t)(Mb + r) * 256 + kb + swz, (char*)SH + ch * 1024);
            async_load16(Bm + (size_t)(Nb + r) * 256 + kb + swz, (char*)SH + 16384 + ch * 1024);
        }
        __syncthreads();
#pragma unroll
        for (int kk = 0; kk < 64; kk += 32) {
            bf16x8 af[4], bfr[4];
#pragma unroll
            for (int i = 0; i < 4; i++) {
                int rr = wm + 16 * i + mrow;
                af[i] = *(const bf16x8*)&SH[rr * 64 + ((((kk >> 3) + quad) ^ (rr & 7)) << 3)];
            }
#pragma unroll
            for (int j = 0; j < 4; j++) {
                int rr = wn + 16 * j + mrow;
                bfr[j] = *(const bf16x8*)&SH[8192 + rr * 64 + ((((kk >> 3) + quad) ^ (rr & 7)) << 3)];
            }
#pragma unroll
            for (int i = 0; i < 4; i++)
#pragma unroll
                for (int j = 0; j < 4; j++)
                    acc[i][j] = __builtin_amdgcn_mfma_f32_16x16x32_bf16(af[i], bfr[j], acc[i][j], 0, 0, 0);
        }
        __syncthreads();
    }
    // ---- epilogue: C tile (128x128 bf16) into LDS ----
    unsigned short* Cs = SH;
#pragma unroll
    for (int i = 0; i < 4; i++)
#pragma unroll
        for (int j = 0; j < 4; j++)
#pragma unroll
            for (int r = 0; r < 4; r++) {
                int row = wm + 16 * i + quad * 4 + r;
                int col = wn + 16 * j + mrow;
                Cs[row * 128 + col] = f2bf(acc[i][j][r]);
            }
    __syncthreads();
    // coalesced Cs -> Bu (uint4 per thread, 8 iters)
#pragma unroll
    for (int it = 0; it < 8; it++) {
        int o = tid * 16 + it * 4096;       // byte offset in Cs
        int row = o >> 8, colb = o & 255;
        uint4 v = *(const uint4*)((const char*)Cs + o);
        *(uint4*)((char*)Bu + (size_t)(Mb + row) * 2048 + (size_t)Nb * 2 + colb) = v;
    }
    // fused per-chunk scan carry: this block is chunk c of batch b, 64 complex chains.
    int d = Nb >> 9;
    int b = Mb >> 13;
    int c = (Mb >> 7) & 63;
    float sr = 0.f, si = 0.f;
    float2 A2 = make_float2(0.f, 0.f);
    int p = 0;
    if (tid < 128) {
        int j = tid & 63, half = tid >> 6;
        p = ((Nb & 511) >> 1) + j;
        A2 = Lbar[d * 256 + p];
        const unsigned int* C32 = (const unsigned int*)Cs;
        int r0 = half * 64;
        if (d == 0) {
            for (int t = 0; t < 64; t++) {
                unsigned int v = C32[(r0 + t) * 64 + j];
                float zr = bf2f(v & 0xffffu), zi = bf2f(v >> 16);
                float nr = A2.x * sr - A2.y * si + zr;
                float ni = A2.x * si + A2.y * sr + zi;
                sr = nr; si = ni;
            }
        } else {
            for (int t = 63; t >= 0; t--) {
                unsigned int v = C32[(r0 + t) * 64 + j];
                float zr = bf2f(v & 0xffffu), zi = bf2f(v >> 16);
                float nr = A2.x * sr - A2.y * si + zr;
                float ni = A2.x * si + A2.y * sr + zi;
                sr = nr; si = ni;
            }
        }
        if (half == 1) Sbuf[j] = make_float2(sr, si);
    }
    __syncthreads();
    if (tid < 64) {
        // here (sr,si) = half-0 partial: fwd S0 (rows 0..63), bwd S0' (rows 63..0)
        float2 S1 = Sbuf[tid];   // half-1 partial: fwd S1 (64..127), bwd S1' (127..64)
        float a64r = A2.x, a64i = A2.y;
#pragma unroll
        for (int k = 0; k < 6; k++) {  // A^(2^6) = A^64
            float nr = a64r * a64r - a64i * a64i;
            float ni = 2.f * a64r * a64i;
            a64r = nr; a64i = ni;
        }
        float cr, ci;
        float2 hv;
        if (d == 0) {   // full carry = A^64 * S0 + S1 ; inner partial = S0
            cr = a64r * sr - a64i * si + S1.x;
            ci = a64r * si + a64i * sr + S1.y;
            hv = make_float2(sr, si);
        } else {        // full carry = S0' + A^64 * S1' ; inner partial = S1'
            cr = sr + a64r * S1.x - a64i * S1.y;
            ci = si + a64r * S1.y + a64i * S1.x;
            hv = S1;
        }
        size_t cidx = ((size_t)(d * 4 + b) * NC + c) * 256 + p;
        carry[cidx] = make_float2(cr, ci);
        halfc[cidx] = hv;
    }
}

// ---------------- scan fix: half-chunk blocks, 4 chains/thread, uint4 loads ----------------
// grid (128 sub-chunks, 4 batches) x 128 thr: d = tid>>6, p0 = (tid&63)*4.
// Each thread owns 4 adjacent chains (p0..p0+3): 16B/lane fully-coalesced row access
// (wave covers 1KB of the 2KB row), 4 independent FMA chains for ILP.
// sub-chunk m = 2c+h covers rows [c*128 + h*64, +64).
// fwd entering state: h=0 -> P(c); h=1 -> A^64*P(c) + S0(c).
// bwd entering state: h=1 -> R(c); h=0 -> A^64*R(c) + S1'(c).
__global__ __launch_bounds__(128) void scan_fix_kernel(uint4* __restrict__ XSu4,
                                                       const float2* __restrict__ Lbar,
                                                       const float2* __restrict__ carry,
                                                       const float2* __restrict__ halfc) {
    int m = blockIdx.x, b = blockIdx.y;
    int c = m >> 1, h = m & 1;
    int d = threadIdx.x >> 6;
    int p0 = (threadIdx.x & 63) * 4;
    float ar[4], ai[4], a64r[4], a64i[4], a128r[4], a128i[4], sr[4], si[4];
#pragma unroll
    for (int j = 0; j < 4; j++) {
        float2 A = Lbar[d * 256 + p0 + j];
        ar[j] = A.x; ai[j] = A.y;
        float xr = A.x, xi = A.y;
#pragma unroll
        for (int k = 0; k < 6; k++) {  // A^64
            float nr = xr * xr - xi * xi;
            float ni = 2.f * xr * xi;
            xr = nr; xi = ni;
        }
        a64r[j] = xr; a64i[j] = xi;
        a128r[j] = xr * xr - xi * xi;
        a128i[j] = 2.f * xr * xi;
        sr[j] = 0.f; si[j] = 0.f;
    }
    const float4* cb4 = (const float4*)(carry + ((size_t)(d * 4 + b) * NC) * 256 + p0);
    const float4* hb4 = (const float4*)(halfc + (((size_t)(d * 4 + b) * NC + c) * 256 + p0));
    if (d == 0) {
        for (int j = 0; j < c; j++) {
            float4 c01 = cb4[j * 128];
            float4 c23 = cb4[j * 128 + 1];
            float cx[4] = {c01.x, c01.z, c23.x, c23.z};
            float cy[4] = {c01.y, c01.w, c23.y, c23.w};
#pragma unroll
            for (int q = 0; q < 4; q++) {
                float nr = a128r[q] * sr[q] - a128i[q] * si[q] + cx[q];
                float ni = a128r[q] * si[q] + a128i[q] * sr[q] + cy[q];
                sr[q] = nr; si[q] = ni;
            }
        }
        if (h) {
            float4 h01 = hb4[0], h23 = hb4[1];
            float hx[4] = {h01.x, h01.z, h23.x, h23.z};
            float hy[4] = {h01.y, h01.w, h23.y, h23.w};
#pragma unroll
            for (int q = 0; q < 4; q++) {
                float nr = a64r[q] * sr[q] - a64i[q] * si[q] + hx[q];
                float ni = a64r[q] * si[q] + a64i[q] * sr[q] + hy[q];
                sr[q] = nr; si[q] = ni;
            }
        }
    } else {
        for (int j = NC - 1; j > c; j--) {
            float4 c01 = cb4[j * 128];
            float4 c23 = cb4[j * 128 + 1];
            float cx[4] = {c01.x, c01.z, c23.x, c23.z};
            float cy[4] = {c01.y, c01.w, c23.y, c23.w};
#pragma unroll
            for (int q = 0; q < 4; q++) {
                float nr = a128r[q] * sr[q] - a128i[q] * si[q] + cx[q];
                float ni = a128r[q] * si[q] + a128i[q] * sr[q] + cy[q];
                sr[q] = nr; si[q] = ni;
            }
        }
        if (!h) {
            float4 h01 = hb4[0], h23 = hb4[1];
            float hx[4] = {h01.x, h01.z, h23.x, h23.z};
            float hy[4] = {h01.y, h01.w, h23.y, h23.w};
#pragma unroll
            for (int q = 0; q < 4; q++) {
                float nr = a64r[q] * sr[q] - a64i[q] * si[q] + hx[q];
                float ni = a64r[q] * si[q] + a64i[q] * sr[q] + hy[q];
                sr[q] = nr; si[q] = ni;
            }
        }
    }
    // uint4 index: (b*8192 + l)*128 + d*64 + p0/4
    size_t base = (size_t)b * L_DIM * 128 + d * 64 + (p0 >> 2);
    int l0 = c * 128 + h * 64;
    if (d == 0) {
#pragma unroll 8
        for (int t = 0; t < 64; t++) {
            size_t idx = base + (size_t)(l0 + t) * 128;
            uint4 v = XSu4[idx];
            unsigned int u[4] = {v.x, v.y, v.z, v.w};
#pragma unroll
            for (int q = 0; q < 4; q++) {
                float zr = bf2f(u[q] & 0xffffu), zi = bf2f(u[q] >> 16);
                float nr = ar[q] * sr[q] - ai[q] * si[q] + zr;
                float ni = ar[q] * si[q] + ai[q] * sr[q] + zi;
                sr[q] = nr; si[q] = ni;
                u[q] = (unsigned int)f2bf(sr[q]) | ((unsigned int)f2bf(si[q]) << 16);
            }
            XSu4[idx] = make_uint4(u[0], u[1], u[2], u[3]);
        }
    } else {
#pragma unroll 8
        for (int t = 63; t >= 0; t--) {
            size_t idx = base + (size_t)(l0 + t) * 128;
            uint4 v = XSu4[idx];
            unsigned int u[4] = {v.x, v.y, v.z, v.w};
#pragma unroll
            for (int q = 0; q < 4; q++) {
                float zr = bf2f(u[q] & 0xffffu), zi = bf2f(u[q] >> 16);
                float nr = ar[q] * sr[q] - ai[q] * si[q] + zr;
                float ni = ar[q] * si[q] + ai[q] * sr[q] + zi;
                sr[q] = nr; si[q] = ni;
                u[q] = (unsigned int)f2bf(sr[q]) | ((unsigned int)f2bf(si[q]) << 16);
            }
            XSu4[idx] = make_uint4(u[0], u[1], u[2], u[3]);
        }
    }
}

// ---------------- K3 half: one K=512 GEMM with statically-bound accumulator ----------------
static __device__ __forceinline__ void k3_half(const unsigned short* __restrict__ XS,
                                               const unsigned short* __restrict__ B3h,
                                               unsigned short* As, unsigned short* Bs,
                                               int Mb, int Hb, int coff,
                                               int wm, int wn, int mrow, int quad,
                                               int lr, int swz, int wv,
                                               f32x4 (&acc)[4][4]) {
    for (int kb = 0; kb < 512; kb += 64) {
#pragma unroll
        for (int ch = wv; ch < 16; ch += 4) {
            int r = ch * 8 + lr;
            async_load16(XS + (size_t)(Mb + r) * 1024 + coff + kb + swz, (char*)As + ch * 1024);
            async_load16(B3h + (size_t)(Hb + r) * 512 + kb + swz, (char*)Bs + ch * 1024);
        }
        __syncthreads();
#pragma unroll
        for (int kk = 0; kk < 64; kk += 32) {
            bf16x8 af[4], bfr[4];
#pragma unroll
            for (int i = 0; i < 4; i++) {
                int rr = wm + 16 * i + mrow;
                af[i] = *(const bf16x8*)&As[rr * 64 + ((((kk >> 3) + quad) ^ (rr & 7)) << 3)];
            }
#pragma unroll
            for (int j = 0; j < 4; j++) {
                int rr = wn + 16 * j + mrow;
                bfr[j] = *(const bf16x8*)&Bs[rr * 64 + ((((kk >> 3) + quad) ^ (rr & 7)) << 3)];
            }
#pragma unroll
            for (int i = 0; i < 4; i++)
#pragma unroll
                for (int j = 0; j < 4; j++)
                    acc[i][j] = __builtin_amdgcn_mfma_f32_16x16x32_bf16(af[i], bfr[j], acc[i][j], 0, 0, 0);
        }
        __syncthreads();
    }
}

// ---------------- K3: out = gelu(xs_f·Cf + Df*x) + gelu(W·Cb + Db*x) ----------------
// Grid (Hb=2, Mb=256): the 2 blocks sharing an XS row-tile are dispatch-adjacent.
__global__ __launch_bounds__(256, 2) void k3_gemm(const unsigned short* __restrict__ XS,
                                                  const unsigned short* __restrict__ B3,
                                                  const unsigned short* __restrict__ xbf,
                                                  const float* __restrict__ Df,
                                                  const float* __restrict__ Db,
                                                  float* __restrict__ out) {
    __shared__ unsigned short As[128 * 64];
    __shared__ unsigned short Bs[128 * 64];
    int tid = threadIdx.x;
    int lane = tid & 63, wv = tid >> 6;          // 4 waves
    int wm = (wv >> 1) * 64, wn = (wv & 1) * 64; // 64x64 quadrant
    int Mb = blockIdx.y * 128, Hb = blockIdx.x * 128;
    int lr = lane >> 3;
    int swz = ((lane & 7) ^ lr) * 8;
    int mrow = lane & 15, quad = lane >> 4;
    f32x4 accf[4][4], accb[4][4];
#pragma unroll
    for (int i = 0; i < 4; i++)
#pragma unroll
        for (int j = 0; j < 4; j++) {
            accf[i][j] = (f32x4){0.f, 0.f, 0.f, 0.f};
            accb[i][j] = (f32x4){0.f, 0.f, 0.f, 0.f};
        }
    // forward half (k-cols 0..511), then backward half (512..1023) — statically bound accs
    k3_half(XS, B3,          As, Bs, Mb, Hb, 0,   wm, wn, mrow, quad, lr, swz, wv, accf);
    k3_half(XS, B3 + 131072, As, Bs, Mb, Hb, 512, wm, wn, mrow, quad, lr, swz, wv, accb);
#pragma unroll
    for (int i = 0; i < 4; i++)
#pragma unroll
        for (int j = 0; j < 4; j++) {
            int h = Hb + wn + 16 * j + mrow;
            float df = Df[h], db = Db[h];
#pragma unroll
            for (int r = 0; r < 4; r++) {
                int row = Mb + wm + 16 * i + quad * 4 + r;
                float xv = bf2f((unsigned int)xbf[(size_t)row * 256 + h]);
                float yf = accf[i][j][r] + df * xv;
                float yb = accb[i][j][r] + db * xv;
                out[(size_t)row * 256 + h] = gelu_f(yf) + gelu_f(yb);
            }
        }
}

// ---------------- launcher ----------------
extern "C" void kernel_launch(void* const* d_in, const int* in_sizes, int n_in,
                              void* d_out, int out_size, void* d_ws, size_t ws_size,
                              hipStream_t stream) {
    const float* x   = (const float*)d_in[0];
    const float* fLr = (const float*)d_in[1];
    const float* fIm = (const float*)d_in[2];
    const float* fLd = (const float*)d_in[3];
    const float* fBr = (const float*)d_in[4];
    const float* fBi = (const float*)d_in[5];
    const float* fCr = (const float*)d_in[6];
    const float* fCi = (const float*)d_in[7];
    const float* fD  = (const float*)d_in[8];
    const float* bLr = (const float*)d_in[9];
    const float* bIm = (const float*)d_in[10];
    const float* bLd = (const float*)d_in[11];
    const float* bBr = (const float*)d_in[12];
    const float* bBi = (const float*)d_in[13];
    const float* bCr = (const float*)d_in[14];
    const float* bCi = (const float*)d_in[15];
    const float* bD  = (const float*)d_in[16];
    float* out = (float*)d_out;

    char* ws = (char*)d_ws;
    unsigned short* xbf  = (unsigned short*)(ws);                               // 16 MiB
    unsigned short* Bu   = (unsigned short*)(ws + 16777216);                    // 64 MiB (Bu, then xs in-place)
    unsigned short* Bmat = (unsigned short*)(ws + 16777216 + 67108864);         // 512 KiB
    unsigned short* B3   = (unsigned short*)(ws + 16777216 + 67108864 + 524288);// 512 KiB
    float2* LbarWS = (float2*)(ws + 16777216 + 67108864 + 1048576);             // 4 KiB
    float2* carry  = (float2*)(ws + 16777216 + 67108864 + 1048576 + 4096);      // 1 MiB
    float2* halfc  = (float2*)(ws + 16777216 + 67108864 + 1048576 + 4096 + 1048576); // 1 MiB

    prep_kernel<<<10242, 256, 0, stream>>>(fLr, fIm, fLd, fBr, fBi, fCr, fCi,
                                           bLr, bIm, bLd, bBr, bBi, bCr, bCi,
                                           (const float4*)x, (ushort4*)xbf,
                                           Bmat, B3, LbarWS);
    k1_gemm<<<dim3(8, 256), 256, 0, stream>>>(xbf, Bmat, Bu, LbarWS, carry, halfc);
    scan_fix_kernel<<<dim3(128, 4), 128, 0, stream>>>((uint4*)Bu, LbarWS, carry, halfc);
    k3_gemm<<<dim3(2, 256), 256, 0, stream>>>(Bu, B3, xbf, fD, bD, out);
}

// Round 9
// 202.745 us; speedup vs baseline: 1.0691x; 1.0691x over previous
//
#include <hip/hip_runtime.h>
#include <math.h>

#define B_DIM 4
#define L_DIM 8192
#define H_DIM 256
#define P_DIM 256
#define M_DIM (B_DIM * L_DIM)   // 32768 rows (b,l) flattened
#define NC 64                   // scan chunks per chain (chunk = 128 rows = one k1 tile)
#define LC 128                  // chunk length

typedef __attribute__((ext_vector_type(8))) short bf16x8;
typedef __attribute__((ext_vector_type(4))) float f32x4;

static __device__ __forceinline__ float bf2f(unsigned int u) {
    union { unsigned int i; float f; } v; v.i = u << 16; return v.f;
}
static __device__ __forceinline__ unsigned short f2bf(float f) {
    union { float f; unsigned int i; } v; v.f = f;
    unsigned int r = v.i + 0x7FFFu + ((v.i >> 16) & 1u);
    return (unsigned short)(r >> 16);
}
// tanh-form GELU; |gelu_tanh - gelu_erf| <= ~0.003 absolute, far under threshold
static __device__ __forceinline__ float gelu_f(float x) {
    float z = 0.7978845608028654f * (x + 0.044715f * x * x * x);
    float e = __expf(2.0f * z);
    float t = 1.0f - 2.0f / (e + 1.0f);   // tanh(z)
    return 0.5f * x * (1.0f + t);
}
// async global->LDS DMA, 16B per lane; LDS dest = base + lane*16 (wave-uniform base)
static __device__ __forceinline__ void async_load16(const void* g, void* l) {
    __builtin_amdgcn_global_load_lds(
        (const __attribute__((address_space(1))) unsigned int*)g,
        (__attribute__((address_space(3))) unsigned int*)l, 16, 0, 0);
}

// ---------------- combined prep + xcast kernel ----------------
// gid < 2097152: xcast (float4 -> bf16x4).  Then Bmat / B3 / Lbar ranges.
// Layouts (INTERLEAVED complex): Bu col index k = d*512 + 2p + comp.
// Bmat[k][h] (1024x256 bf16); B3[d][h][k'] (2x256x512 bf16), k'=2p+comp;
// LbarWS[d*256+p] = (Lbar_r, Lbar_i) fp32.
__global__ void prep_kernel(const float* fLr, const float* fIm, const float* fLd,
                            const float* fBr, const float* fBi,
                            const float* fCr, const float* fCi,
                            const float* bLr, const float* bIm, const float* bLd,
                            const float* bBr, const float* bBi,
                            const float* bCr, const float* bCi,
                            const float4* __restrict__ x4, ushort4* __restrict__ xb,
                            unsigned short* Bmat, unsigned short* B3, float2* LbarWS) {
    int gid = blockIdx.x * 256 + threadIdx.x;
    if (gid < 2097152) {
        float4 v = x4[gid];
        ushort4 o;
        o.x = f2bf(v.x); o.y = f2bf(v.y); o.z = f2bf(v.z); o.w = f2bf(v.w);
        xb[gid] = o;
        return;
    }
    int g1 = gid - 2097152;
    if (g1 < 262144) {
        // Bmat
        int k = g1 >> 8, h = g1 & 255;
        int d = k >> 9, pc = k & 511, p = pc >> 1, comp = pc & 1;
        const float* LR = d ? bLr : fLr;
        const float* IM = d ? bIm : fIm;
        const float* LD = d ? bLd : fLd;
        const float* BR = d ? bBr : fBr;
        const float* BI = d ? bBi : fBi;
        float Lr = -expf(LR[p]);
        float Li = IM[p];
        float Delta = expf(LD[p]);
        float ea = expf(Lr * Delta);
        float bd = Li * Delta;
        float Lbr = ea * cosf(bd);
        float Lbi = ea * sinf(bd);
        float denom = fmaxf(Lr * Lr + Li * Li, 1e-12f);
        float ivr = Lr / denom, ivi = -Li / denom;
        float dr = Lbr - 1.0f, di = Lbi;
        float cr = ivr * dr - ivi * di;
        float ci = ivr * di + ivi * dr;
        float br = BR[p * 256 + h], bi = BI[p * 256 + h];
        float val = comp ? (cr * bi + ci * br) : (cr * br - ci * bi);
        Bmat[g1] = f2bf(val);
    } else if (g1 < 524288) {
        int g2 = g1 - 262144;
        int d = g2 >> 17;
        int rem = g2 & 131071;
        int h = rem >> 9;
        int kk = rem & 511;
        int p = kk >> 1, comp = kk & 1;
        const float* CR = d ? bCr : fCr;
        const float* CI = d ? bCi : fCi;
        float val = comp ? -CI[h * 256 + p] : CR[h * 256 + p];
        B3[g2] = f2bf(val);
    } else if (g1 < 524800) {
        int g2 = g1 - 524288;          // 0..511
        int d = g2 >> 8, p = g2 & 255;
        const float* LR = d ? bLr : fLr;
        const float* IM = d ? bIm : fIm;
        const float* LD = d ? bLd : fLd;
        float Lr = -expf(LR[p]); float Li = IM[p]; float Delta = expf(LD[p]);
        float ea = expf(Lr * Delta); float bd = Li * Delta;
        LbarWS[g2] = make_float2(ea * cosf(bd), ea * sinf(bd));
    }
}

// ---------------- K1: Bu = xbf(32768x256) @ Bmat(1024x256)^T -> Bu bf16 (32768x1024) ----------------
// m97 geometry: 256 threads / 4 waves, 128x128 tile, wave = 64x64 quadrant (4x4 f32x4 accs),
// BK=64, XOR-swizzled LDS chunks (16B chunk q of row r at q^(r&7); 0 conflicts verified).
// Grid (Mb fast, Nb slow): sequential A stream; A (16MB) stays L3-resident across Nb passes.
// Epilogue: C tile -> LDS -> coalesced Bu store + fused scan partials at QUARTER-chunk
// granularity (4x 32-row partials + full-chunk carry) enabling 32-step scan_fix blocks.
__global__ __launch_bounds__(256, 2) void k1_gemm(const unsigned short* __restrict__ A,
                                                  const unsigned short* __restrict__ Bm,
                                                  unsigned short* __restrict__ Bu,
                                                  const float2* __restrict__ Lbar,
                                                  float2* __restrict__ carry,
                                                  float2* __restrict__ qpart) {
    __shared__ unsigned short SH[16384];   // 32 KB: As=SH[0:8192], Bs=SH[8192:16384]; Cs overlays all
    __shared__ float2 Sbuf[256];           // 4 quarters x 64 chains
    int tid = threadIdx.x;
    int lane = tid & 63, wv = tid >> 6;          // 4 waves
    int wm = (wv >> 1) * 64, wn = (wv & 1) * 64; // 64x64 quadrant
    int Mb = blockIdx.x * 128, Nb = blockIdx.y * 128;
    int lr = lane >> 3;                 // row within 8-row chunk group
    int swz = ((lane & 7) ^ lr) * 8;    // swizzled source chunk (in shorts)
    f32x4 acc[4][4];
#pragma unroll
    for (int i = 0; i < 4; i++)
#pragma unroll
        for (int j = 0; j < 4; j++) acc[i][j] = (f32x4){0.f, 0.f, 0.f, 0.f};
    int mrow = lane & 15, quad = lane >> 4;
    for (int kb = 0; kb < 256; kb += 64) {
#pragma unroll
        for (int ch = wv; ch < 16; ch += 4) {
            int r = ch * 8 + lr;
            async_load16(A  + (size_t)(Mb + r) * 256 + kb + swz, (char*)SH + ch * 1024);
            async_load16(Bm + (size_t)(Nb + r) * 256 + kb + swz, (char*)SH + 16384 + ch * 1024);
        }
        __syncthreads();
#pragma unroll
        for (int kk = 0; kk < 64; kk += 32) {
            bf16x8 af[4], bfr[4];
#pragma unroll
            for (int i = 0; i < 4; i++) {
                int rr = wm + 16 * i + mrow;
                af[i] = *(const bf16x8*)&SH[rr * 64 + ((((kk >> 3) + quad) ^ (rr & 7)) << 3)];
            }
#pragma unroll
            for (int j = 0; j < 4; j++) {
                int rr = wn + 16 * j + mrow;
                bfr[j] = *(const bf16x8*)&SH[8192 + rr * 64 + ((((kk >> 3) + quad) ^ (rr & 7)) << 3)];
            }
#pragma unroll
            for (int i = 0; i < 4; i++)
#pragma unroll
                for (int j = 0; j < 4; j++)
                    acc[i][j] = __builtin_amdgcn_mfma_f32_16x16x32_bf16(af[i], bfr[j], acc[i][j], 0, 0, 0);
        }
        __syncthreads();
    }
    // ---- epilogue: C tile (128x128 bf16) into LDS ----
    unsigned short* Cs = SH;
#pragma unroll
    for (int i = 0; i < 4; i++)
#pragma unroll
        for (int j = 0; j < 4; j++)
#pragma unroll
            for (int r = 0; r < 4; r++) {
                int row = wm + 16 * i + quad * 4 + r;
                int col = wn + 16 * j + mrow;
                Cs[row * 128 + col] = f2bf(acc[i][j][r]);
            }
    __syncthreads();
    // coalesced Cs -> Bu (uint4 per thread, 8 iters)
#pragma unroll
    for (int it = 0; it < 8; it++) {
        int o = tid * 16 + it * 4096;       // byte offset in Cs
        int row = o >> 8, colb = o & 255;
        uint4 v = *(const uint4*)((const char*)Cs + o);
        *(uint4*)((char*)Bu + (size_t)(Mb + row) * 2048 + (size_t)Nb * 2 + colb) = v;
    }
    // fused quarter-granularity scan partials: this block is chunk c of batch b, 64 chains.
    int d = Nb >> 9;
    int b = Mb >> 13;
    int c = (Mb >> 7) & 63;
    int q = tid >> 6;            // quarter 0..3 (rows q*32 .. q*32+31)
    int j = tid & 63;
    int p = ((Nb & 511) >> 1) + j;
    float2 A2 = Lbar[d * 256 + p];
    float sr = 0.f, si = 0.f;
    {
        const unsigned int* C32 = (const unsigned int*)Cs;
        int r0 = q * 32;
        if (d == 0) {
            for (int t = 0; t < 32; t++) {
                unsigned int v = C32[(r0 + t) * 64 + j];
                float zr = bf2f(v & 0xffffu), zi = bf2f(v >> 16);
                float nr = A2.x * sr - A2.y * si + zr;
                float ni = A2.x * si + A2.y * sr + zi;
                sr = nr; si = ni;
            }
        } else {
            for (int t = 31; t >= 0; t--) {
                unsigned int v = C32[(r0 + t) * 64 + j];
                float zr = bf2f(v & 0xffffu), zi = bf2f(v >> 16);
                float nr = A2.x * sr - A2.y * si + zr;
                float ni = A2.x * si + A2.y * sr + zi;
                sr = nr; si = ni;
            }
        }
        Sbuf[q * 64 + j] = make_float2(sr, si);
    }
    // qpart layout: [((d*4+b)*NC + c)*1024 + q*256 + p]
    size_t cbase = ((size_t)(d * 4 + b) * NC + c);
    qpart[cbase * 1024 + q * 256 + p] = make_float2(sr, si);
    __syncthreads();
    if (tid < 64) {
        float a32r = A2.x, a32i = A2.y;
#pragma unroll
        for (int k = 0; k < 5; k++) {  // A^(2^5) = A^32
            float nr = a32r * a32r - a32i * a32i;
            float ni = 2.f * a32r * a32i;
            a32r = nr; a32i = ni;
        }
        float cr, ci;
        if (d == 0) {   // carry = ((Q0*A32+Q1)*A32+Q2)*A32+Q3
            float2 s = Sbuf[j];
            cr = s.x; ci = s.y;
#pragma unroll
            for (int t = 1; t < 4; t++) {
                float2 Qt = Sbuf[t * 64 + j];
                float nr = a32r * cr - a32i * ci + Qt.x;
                float ni = a32r * ci + a32i * cr + Qt.y;
                cr = nr; ci = ni;
            }
        } else {        // carry = ((Q3*A32+Q2)*A32+Q1)*A32+Q0
            float2 s = Sbuf[3 * 64 + j];
            cr = s.x; ci = s.y;
#pragma unroll
            for (int t = 2; t >= 0; t--) {
                float2 Qt = Sbuf[t * 64 + j];
                float nr = a32r * cr - a32i * ci + Qt.x;
                float ni = a32r * ci + a32i * cr + Qt.y;
                cr = nr; ci = ni;
            }
        }
        carry[cbase * 256 + p] = make_float2(cr, ci);
    }
}

// ---------------- scan fix: quarter-chunk blocks, 4 chains/thread, uint4 loads ----------------
// grid (256 quarter-units, 4 batches) x 128 thr: d = tid>>6, p0 = (tid&63)*4.
// unit mq = c*4 + q covers rows [c*128 + q*32, +32). 2048 waves = 8/CU; serial depth 32.
// fwd entering state: P(c) (fold carries j<c with A^128) then fold quarters t<q with A^32.
// bwd entering state: R(c) (fold carries j>c) then fold quarters t>q with A^32.
__global__ __launch_bounds__(128) void scan_fix_kernel(uint4* __restrict__ XSu4,
                                                       const float2* __restrict__ Lbar,
                                                       const float2* __restrict__ carry,
                                                       const float2* __restrict__ qpart) {
    int mq = blockIdx.x, b = blockIdx.y;
    int c = mq >> 2, q = mq & 3;
    int d = threadIdx.x >> 6;
    int p0 = (threadIdx.x & 63) * 4;
    float ar[4], ai[4], a32r[4], a32i[4], a128r[4], a128i[4], sr[4], si[4];
#pragma unroll
    for (int j = 0; j < 4; j++) {
        float2 A = Lbar[d * 256 + p0 + j];
        ar[j] = A.x; ai[j] = A.y;
        float xr = A.x, xi = A.y;
#pragma unroll
        for (int k = 0; k < 5; k++) {  // A^32
            float nr = xr * xr - xi * xi;
            float ni = 2.f * xr * xi;
            xr = nr; xi = ni;
        }
        a32r[j] = xr; a32i[j] = xi;
        float yr = xr * xr - xi * xi;      // A^64
        float yi = 2.f * xr * xi;
        a128r[j] = yr * yr - yi * yi;      // A^128
        a128i[j] = 2.f * yr * yi;
        sr[j] = 0.f; si[j] = 0.f;
    }
    const float4* cb4 = (const float4*)(carry + ((size_t)(d * 4 + b) * NC) * 256 + p0);
    const float4* qb4 = (const float4*)(qpart + (((size_t)(d * 4 + b) * NC + c) * 1024 + p0));
    if (d == 0) {
        for (int j = 0; j < c; j++) {
            float4 c01 = cb4[j * 128];          // chunk stride: 256 float2 = 128 float4
            float4 c23 = cb4[j * 128 + 1];
            float cx[4] = {c01.x, c01.z, c23.x, c23.z};
            float cy[4] = {c01.y, c01.w, c23.y, c23.w};
#pragma unroll
            for (int t = 0; t < 4; t++) {
                float nr = a128r[t] * sr[t] - a128i[t] * si[t] + cx[t];
                float ni = a128r[t] * si[t] + a128i[t] * sr[t] + cy[t];
                sr[t] = nr; si[t] = ni;
            }
        }
        for (int j = 0; j < q; j++) {
            float4 h01 = qb4[j * 128];          // quarter stride: 256 float2 = 128 float4
            float4 h23 = qb4[j * 128 + 1];
            float hx[4] = {h01.x, h01.z, h23.x, h23.z};
            float hy[4] = {h01.y, h01.w, h23.y, h23.w};
#pragma unroll
            for (int t = 0; t < 4; t++) {
                float nr = a32r[t] * sr[t] - a32i[t] * si[t] + hx[t];
                float ni = a32r[t] * si[t] + a32i[t] * sr[t] + hy[t];
                sr[t] = nr; si[t] = ni;
            }
        }
    } else {
        for (int j = NC - 1; j > c; j--) {
            float4 c01 = cb4[j * 128];
            float4 c23 = cb4[j * 128 + 1];
            float cx[4] = {c01.x, c01.z, c23.x, c23.z};
            float cy[4] = {c01.y, c01.w, c23.y, c23.w};
#pragma unroll
            for (int t = 0; t < 4; t++) {
                float nr = a128r[t] * sr[t] - a128i[t] * si[t] + cx[t];
                float ni = a128r[t] * si[t] + a128i[t] * sr[t] + cy[t];
                sr[t] = nr; si[t] = ni;
            }
        }
        for (int j = 3; j > q; j--) {
            float4 h01 = qb4[j * 128];
            float4 h23 = qb4[j * 128 + 1];
            float hx[4] = {h01.x, h01.z, h23.x, h23.z};
            float hy[4] = {h01.y, h01.w, h23.y, h23.w};
#pragma unroll
            for (int t = 0; t < 4; t++) {
                float nr = a32r[t] * sr[t] - a32i[t] * si[t] + hx[t];
                float ni = a32r[t] * si[t] + a32i[t] * sr[t] + hy[t];
                sr[t] = nr; si[t] = ni;
            }
        }
    }
    // uint4 index: (b*8192 + l)*128 + d*64 + p0/4
    size_t base = (size_t)b * L_DIM * 128 + d * 64 + (p0 >> 2);
    int l0 = c * 128 + q * 32;
    if (d == 0) {
#pragma unroll 16
        for (int t = 0; t < 32; t++) {
            size_t idx = base + (size_t)(l0 + t) * 128;
            uint4 v = XSu4[idx];
            unsigned int u[4] = {v.x, v.y, v.z, v.w};
#pragma unroll
            for (int w = 0; w < 4; w++) {
                float zr = bf2f(u[w] & 0xffffu), zi = bf2f(u[w] >> 16);
                float nr = ar[w] * sr[w] - ai[w] * si[w] + zr;
                float ni = ar[w] * si[w] + ai[w] * sr[w] + zi;
                sr[w] = nr; si[w] = ni;
                u[w] = (unsigned int)f2bf(sr[w]) | ((unsigned int)f2bf(si[w]) << 16);
            }
            XSu4[idx] = make_uint4(u[0], u[1], u[2], u[3]);
        }
    } else {
#pragma unroll 16
        for (int t = 31; t >= 0; t--) {
            size_t idx = base + (size_t)(l0 + t) * 128;
            uint4 v = XSu4[idx];
            unsigned int u[4] = {v.x, v.y, v.z, v.w};
#pragma unroll
            for (int w = 0; w < 4; w++) {
                float zr = bf2f(u[w] & 0xffffu), zi = bf2f(u[w] >> 16);
                float nr = ar[w] * sr[w] - ai[w] * si[w] + zr;
                float ni = ar[w] * si[w] + ai[w] * sr[w] + zi;
                sr[w] = nr; si[w] = ni;
                u[w] = (unsigned int)f2bf(sr[w]) | ((unsigned int)f2bf(si[w]) << 16);
            }
            XSu4[idx] = make_uint4(u[0], u[1], u[2], u[3]);
        }
    }
}

// ---------------- K3 half: one K=512 GEMM with statically-bound accumulator ----------------
static __device__ __forceinline__ void k3_half(const unsigned short* __restrict__ XS,
                                               const unsigned short* __restrict__ B3h,
                                               unsigned short* As, unsigned short* Bs,
                                               int Mb, int Hb, int coff,
                                               int wm, int wn, int mrow, int quad,
                                               int lr, int swz, int wv,
                                               f32x4 (&acc)[4][4]) {
    for (int kb = 0; kb < 512; kb += 64) {
#pragma unroll
        for (int ch = wv; ch < 16; ch += 4) {
            int r = ch * 8 + lr;
            async_load16(XS + (size_t)(Mb + r) * 1024 + coff + kb + swz, (char*)As + ch * 1024);
            async_load16(B3h + (size_t)(Hb + r) * 512 + kb + swz, (char*)Bs + ch * 1024);
        }
        __syncthreads();
#pragma unroll
        for (int kk = 0; kk < 64; kk += 32) {
            bf16x8 af[4], bfr[4];
#pragma unroll
            for (int i = 0; i < 4; i++) {
                int rr = wm + 16 * i + mrow;
                af[i] = *(const bf16x8*)&As[rr * 64 + ((((kk >> 3) + quad) ^ (rr & 7)) << 3)];
            }
#pragma unroll
            for (int j = 0; j < 4; j++) {
                int rr = wn + 16 * j + mrow;
                bfr[j] = *(const bf16x8*)&Bs[rr * 64 + ((((kk >> 3) + quad) ^ (rr & 7)) << 3)];
            }
#pragma unroll
            for (int i = 0; i < 4; i++)
#pragma unroll
                for (int j = 0; j < 4; j++)
                    acc[i][j] = __builtin_amdgcn_mfma_f32_16x16x32_bf16(af[i], bfr[j], acc[i][j], 0, 0, 0);
        }
        __syncthreads();
    }
}

// ---------------- K3: out = gelu(xs_f·Cf + Df*x) + gelu(W·Cb + Db*x) ----------------
// Grid (Mb fast, Hb slow): sequential XS stream per Hb pass; XS L3-resident on 2nd pass.
__global__ __launch_bounds__(256, 2) void k3_gemm(const unsigned short* __restrict__ XS,
                                                  const unsigned short* __restrict__ B3,
                                                  const unsigned short* __restrict__ xbf,
                                                  const float* __restrict__ Df,
                                                  const float* __restrict__ Db,
                                                  float* __restrict__ out) {
    __shared__ unsigned short As[128 * 64];
    __shared__ unsigned short Bs[128 * 64];
    int tid = threadIdx.x;
    int lane = tid & 63, wv = tid >> 6;          // 4 waves
    int wm = (wv >> 1) * 64, wn = (wv & 1) * 64; // 64x64 quadrant
    int Mb = blockIdx.x * 128, Hb = blockIdx.y * 128;
    int lr = lane >> 3;
    int swz = ((lane & 7) ^ lr) * 8;
    int mrow = lane & 15, quad = lane >> 4;
    f32x4 accf[4][4], accb[4][4];
#pragma unroll
    for (int i = 0; i < 4; i++)
#pragma unroll
        for (int j = 0; j < 4; j++) {
            accf[i][j] = (f32x4){0.f, 0.f, 0.f, 0.f};
            accb[i][j] = (f32x4){0.f, 0.f, 0.f, 0.f};
        }
    // forward half (k-cols 0..511), then backward half (512..1023) — statically bound accs
    k3_half(XS, B3,          As, Bs, Mb, Hb, 0,   wm, wn, mrow, quad, lr, swz, wv, accf);
    k3_half(XS, B3 + 131072, As, Bs, Mb, Hb, 512, wm, wn, mrow, quad, lr, swz, wv, accb);
#pragma unroll
    for (int i = 0; i < 4; i++)
#pragma unroll
        for (int j = 0; j < 4; j++) {
            int h = Hb + wn + 16 * j + mrow;
            float df = Df[h], db = Db[h];
#pragma unroll
            for (int r = 0; r < 4; r++) {
                int row = Mb + wm + 16 * i + quad * 4 + r;
                float xv = bf2f((unsigned int)xbf[(size_t)row * 256 + h]);
                float yf = accf[i][j][r] + df * xv;
                float yb = accb[i][j][r] + db * xv;
                out[(size_t)row * 256 + h] = gelu_f(yf) + gelu_f(yb);
            }
        }
}

// ---------------- launcher ----------------
extern "C" void kernel_launch(void* const* d_in, const int* in_sizes, int n_in,
                              void* d_out, int out_size, void* d_ws, size_t ws_size,
                              hipStream_t stream) {
    const float* x   = (const float*)d_in[0];
    const float* fLr = (const float*)d_in[1];
    const float* fIm = (const float*)d_in[2];
    const float* fLd = (const float*)d_in[3];
    const float* fBr = (const float*)d_in[4];
    const float* fBi = (const float*)d_in[5];
    const float* fCr = (const float*)d_in[6];
    const float* fCi = (const float*)d_in[7];
    const float* fD  = (const float*)d_in[8];
    const float* bLr = (const float*)d_in[9];
    const float* bIm = (const float*)d_in[10];
    const float* bLd = (const float*)d_in[11];
    const float* bBr = (const float*)d_in[12];
    const float* bBi = (const float*)d_in[13];
    const float* bCr = (const float*)d_in[14];
    const float* bCi = (const float*)d_in[15];
    const float* bD  = (const float*)d_in[16];
    float* out = (float*)d_out;

    char* ws = (char*)d_ws;
    unsigned short* xbf  = (unsigned short*)(ws);                               // 16 MiB
    unsigned short* Bu   = (unsigned short*)(ws + 16777216);                    // 64 MiB (Bu, then xs in-place)
    unsigned short* Bmat = (unsigned short*)(ws + 16777216 + 67108864);         // 512 KiB
    unsigned short* B3   = (unsigned short*)(ws + 16777216 + 67108864 + 524288);// 512 KiB
    float2* LbarWS = (float2*)(ws + 16777216 + 67108864 + 1048576);             // 4 KiB
    float2* carry  = (float2*)(ws + 16777216 + 67108864 + 1048576 + 4096);      // 1 MiB
    float2* qpart  = (float2*)(ws + 16777216 + 67108864 + 1048576 + 4096 + 1048576); // 4 MiB

    prep_kernel<<<10242, 256, 0, stream>>>(fLr, fIm, fLd, fBr, fBi, fCr, fCi,
                                           bLr, bIm, bLd, bBr, bBi, bCr, bCi,
                                           (const float4*)x, (ushort4*)xbf,
                                           Bmat, B3, LbarWS);
    k1_gemm<<<dim3(256, 8), 256, 0, stream>>>(xbf, Bmat, Bu, LbarWS, carry, qpart);
    scan_fix_kernel<<<dim3(256, 4), 128, 0, stream>>>((uint4*)Bu, LbarWS, carry, qpart);
    k3_gemm<<<dim3(256, 2), 256, 0, stream>>>(Bu, B3, xbf, fD, bD, out);
}